// Round 3
// baseline (17683.946 us; speedup 1.0000x reference)
//
#include <hip/hip_runtime.h>
#include <cstdint>
#include <cstddef>

// ---------------------------------------------------------------------------
// LSTMModel: embed(mask pad=0) -> LSTM(128->256) -> LSTM(256->256) -> FC(256->64) -> softmax
// B=64 T=2048 D=128 H=256 4H=1024 OUT=64 V=1000
//
// Round 2: round-0 pipeline made ws-size-adaptive. Hypothesis for r1 abort:
// unconditional ~387MB carve from d_ws overflowed ws_size -> GPU fault.
// Now the T axis is chunked (CH chosen from ws_size at runtime, constant
// across calls -> graph-safe); LSTM (h,c) state persists in ws between
// chunk launches; XG/HB chunk buffers are reused across pipeline stages.
//  - f16 storage (values ~0.03-0.3; f16 rel err 2^-11 << tolerance)
//  - projections: mfma_f32_16x16x32_f16 GEMM, 128x128 tile, biases folded in
//  - recurrence: one WG/batch, 1024 thr (one per gate), packed Whh streamed
//    as coalesced uint4 from L2, h in LDS, c in regs, v_dot2 accumulate
//  - e lives in d_out (FC chunk i overwrites exactly the e-rows it consumed;
//    both are 256 B/row)
// ---------------------------------------------------------------------------

typedef _Float16 half_t;
typedef _Float16 half8 __attribute__((ext_vector_type(8)));
typedef _Float16 half2t __attribute__((ext_vector_type(2)));
typedef float floatx4 __attribute__((ext_vector_type(4)));

#define B_   64
#define T_   2048
#define D_   128
#define H_   256
#define G4_  1024
#define OUT_ 64
#define MTOT (B_ * T_)

#if defined(__has_builtin)
#if __has_builtin(__builtin_amdgcn_fdot2)
#define HAVE_FDOT2 1
#endif
#endif

__device__ __forceinline__ float dot2acc(unsigned w, unsigned h, float acc) {
  half2t a = __builtin_bit_cast(half2t, w);
  half2t b = __builtin_bit_cast(half2t, h);
#ifdef HAVE_FDOT2
  return __builtin_amdgcn_fdot2(a, b, acc, false);
#else
  return acc + (float)a[0] * (float)b[0] + (float)a[1] * (float)b[1];
#endif
}

// ---------------- prep kernels ----------------

__global__ __launch_bounds__(256) void k_cvt_f16(const float* __restrict__ in,
                                                 half_t* __restrict__ out, int n) {
  int i = blockIdx.x * 256 + threadIdx.x;
  if (i < n) out[i] = (half_t)in[i];
}

// Whh [1024][256] f32 -> wp[(kc*1024 + j)*8 + e] = Whh[j][kc*8+e]  (f16)
__global__ __launch_bounds__(256) void k_pack_whh(const float* __restrict__ whh,
                                                  half_t* __restrict__ wp) {
  int i = blockIdx.x * 256 + threadIdx.x;      // 262144 total
  int e  = i & 7;
  int j  = (i >> 3) & 1023;
  int kc = i >> 13;
  wp[i] = (half_t)whh[j * 256 + kc * 8 + e];
}

__global__ __launch_bounds__(256) void k_bias(const float* __restrict__ a,
                                              const float* __restrict__ b,
                                              float* __restrict__ out, int n) {
  int i = blockIdx.x * 256 + threadIdx.x;
  if (i < n) out[i] = a[i] + b[i];
}

// fc_W [64][256] -> fcwt[k*64 + l] = fc_W[l][k]
__global__ __launch_bounds__(256) void k_fcwt(const float* __restrict__ fcw,
                                              float* __restrict__ fcwt) {
  int i = blockIdx.x * 256 + threadIdx.x;      // 16384 total
  fcwt[i] = fcw[(i & 63) * 256 + (i >> 6)];
}

// ---------------- embedding ----------------

__global__ __launch_bounds__(256) void k_embed(const int* __restrict__ x,
                                               const float* __restrict__ tab,
                                               half_t* __restrict__ e) {
  const long i = (long)blockIdx.x * 256 + threadIdx.x;   // MTOT*16 threads
  const long m = i >> 4;
  const int ch = (int)(i & 15) * 8;
  const int xi = x[m];
  half8 v;
  #pragma unroll
  for (int q = 0; q < 8; ++q) v[q] = (half_t)0.f;
  if (xi != 0) {
    const float* p = tab + (long)xi * D_ + ch;
    #pragma unroll
    for (int q = 0; q < 8; ++q) v[q] = (half_t)p[q];
  }
  *(half8*)(e + m * D_ + ch) = v;
}

// ---------------- f16 MFMA GEMM ----------------
// C[r][N] = A[row(r)][K] @ Wt[N][K]^T + bias ;  row(r) = (r>>rowShift)*strideB + toff + (r&mask)
// tile 128x128, BK=32, 256 threads (4 waves, 64x64 quadrant each)

__global__ __launch_bounds__(256) void k_gemm_f16(const half_t* __restrict__ A,
                                                  const half_t* __restrict__ Wt,
                                                  const float* __restrict__ bias,
                                                  half_t* __restrict__ C,
                                                  int K, int N,
                                                  int rowShift, int strideB, int toff) {
  __shared__ half_t As[128][40];
  __shared__ half_t Bs[128][40];
  const int tid  = threadIdx.x;
  const int lane = tid & 63;
  const int wave = tid >> 6;
  const int wr = wave >> 1, wc = wave & 1;
  const int r0 = blockIdx.x * 128;
  const int n0 = blockIdx.y * 128;
  const int srow = tid >> 2;
  const int schunk = (tid & 3) * 8;
  const int rmask = (1 << rowShift) - 1;

  floatx4 zero = {0.f, 0.f, 0.f, 0.f};
  floatx4 acc[4][4];
  for (int i = 0; i < 4; ++i)
    for (int j = 0; j < 4; ++j) acc[i][j] = zero;

  const int ra = r0 + srow, rb = r0 + srow + 64;
  const half_t* ArowA = A + ((long)(ra >> rowShift) * strideB + toff + (ra & rmask)) * K;
  const half_t* ArowB = A + ((long)(rb >> rowShift) * strideB + toff + (rb & rmask)) * K;

  for (int k0 = 0; k0 < K; k0 += 32) {
    *(uint4*)(&As[srow][schunk])      = *(const uint4*)(ArowA + k0 + schunk);
    *(uint4*)(&As[srow + 64][schunk]) = *(const uint4*)(ArowB + k0 + schunk);
    const half_t* Bp = Wt + (long)(n0 + srow) * K + k0 + schunk;
    *(uint4*)(&Bs[srow][schunk])      = *(const uint4*)(Bp);
    *(uint4*)(&Bs[srow + 64][schunk]) = *(const uint4*)(Bp + 64L * K);
    __syncthreads();

    const int kq = (lane >> 4) * 8;
    const int fr = lane & 15;
    half8 af[4], bf[4];
    #pragma unroll
    for (int i = 0; i < 4; ++i) af[i] = *(const half8*)(&As[wr * 64 + i * 16 + fr][kq]);
    #pragma unroll
    for (int i = 0; i < 4; ++i) bf[i] = *(const half8*)(&Bs[wc * 64 + i * 16 + fr][kq]);
    #pragma unroll
    for (int mi = 0; mi < 4; ++mi)
      #pragma unroll
      for (int ni = 0; ni < 4; ++ni)
        acc[mi][ni] = __builtin_amdgcn_mfma_f32_16x16x32_f16(af[mi], bf[ni], acc[mi][ni], 0, 0, 0);
    __syncthreads();
  }

  // C/D layout: col = lane&15, row = (lane>>4)*4 + reg
  const int fr = lane & 15, fq = lane >> 4;
  for (int ni = 0; ni < 4; ++ni) {
    const int gcol = n0 + wc * 64 + ni * 16 + fr;
    const float bv = bias[gcol];
    for (int mi = 0; mi < 4; ++mi) {
      const long grow = r0 + wr * 64 + mi * 16 + fq * 4;
      #pragma unroll
      for (int r = 0; r < 4; ++r)
        C[(grow + r) * (long)N + gcol] = (half_t)(acc[mi][ni][r] + bv);
    }
  }
}

// ---------------- LSTM recurrence (chunked, persistent state) ----------------
// xg chunk-local [B][steps][1024] f16 (biases included), Wp packed [32][1024][8],
// hout chunk-local [B][steps][256] f16. Gate order i,f,g,o.

__global__ __launch_bounds__(1024) void k_lstm(const half_t* __restrict__ xg,
                                               const uint4* __restrict__ Wp,
                                               half_t* __restrict__ hout,
                                               float* __restrict__ c_state,
                                               half_t* __restrict__ h_state,
                                               int steps, int first) {
  const int b = blockIdx.x;
  const int j = threadIdx.x;
  __shared__ float gsh[1024];
  __shared__ __align__(16) half_t hsh[256];
  float c = 0.f;
  if (j < H_) {
    if (first) {
      hsh[j] = (half_t)0.f;
    } else {
      hsh[j] = h_state[b * H_ + j];
      c = c_state[b * H_ + j];
    }
  }

  const uint4*  wp     = Wp + j;                     // row stride 1024 uint4
  const half_t* xp     = xg + (long)b * steps * G4_ + j;
  half_t*       hp_out = hout + (long)b * steps * H_;

  for (int t = 0; t < steps; ++t) {
    __syncthreads();                 // h(t-1) visible to all
    float acc = (float)xp[(long)t * G4_];
    const uint4* hv4 = (const uint4*)hsh;
    #pragma unroll 8
    for (int kc = 0; kc < 32; ++kc) {
      uint4 w  = wp[(long)kc * G4_]; // coalesced 16B/lane from L2
      uint4 h4 = hv4[kc];            // LDS broadcast
      acc = dot2acc(w.x, h4.x, acc);
      acc = dot2acc(w.y, h4.y, acc);
      acc = dot2acc(w.z, h4.z, acc);
      acc = dot2acc(w.w, h4.w, acc);
    }
    gsh[j] = acc;
    __syncthreads();
    if (j < H_) {
      float ig = 1.f / (1.f + __expf(-gsh[j]));
      float fg = 1.f / (1.f + __expf(-gsh[H_ + j]));
      float gg = tanhf(gsh[2 * H_ + j]);
      float og = 1.f / (1.f + __expf(-gsh[3 * H_ + j]));
      c = fg * c + ig * gg;
      float h = og * tanhf(c);
      hp_out[(long)t * H_ + j] = (half_t)h;
      hsh[j] = (half_t)h;            // race-free: readers wait at top barrier
    }
  }
  if (j < H_) {
    c_state[b * H_ + j] = c;
    h_state[b * H_ + j] = hsh[j];
  }
}

// ---------------- FC + softmax: one wave per chunk row ----------------

__global__ __launch_bounds__(256) void k_fc_softmax(const half_t* __restrict__ h2,
                                                    const float* __restrict__ fcwt,
                                                    const float* __restrict__ fcb,
                                                    float* __restrict__ out,
                                                    int rowShift, int strideB, int toff) {
  const int lane = threadIdx.x & 63;
  const int r = blockIdx.x * 4 + (threadIdx.x >> 6);
  const half_t* hr = h2 + (long)r * H_;
  float acc = fcb[lane];
  for (int kc = 0; kc < 32; ++kc) {
    uint4 hv = *(const uint4*)(hr + kc * 8);   // same addr across wave: broadcast
    unsigned hu[4] = {hv.x, hv.y, hv.z, hv.w};
    #pragma unroll
    for (int p = 0; p < 4; ++p) {
      half2t hh = __builtin_bit_cast(half2t, hu[p]);
      acc += (float)hh[0] * fcwt[(kc * 8 + p * 2) * 64 + lane];
      acc += (float)hh[1] * fcwt[(kc * 8 + p * 2 + 1) * 64 + lane];
    }
  }
  float m = acc;
  #pragma unroll
  for (int off = 32; off > 0; off >>= 1) m = fmaxf(m, __shfl_xor(m, off));
  float e = __expf(acc - m);
  float s = e;
  #pragma unroll
  for (int off = 32; off > 0; off >>= 1) s += __shfl_xor(s, off);
  const long outrow = (long)(r >> rowShift) * strideB + toff + (r & ((1 << rowShift) - 1));
  out[outrow * OUT_ + lane] = e / s;
}

// ---------------- launch ----------------

extern "C" void kernel_launch(void* const* d_in, const int* in_sizes, int n_in,
                              void* d_out, int out_size, void* d_ws, size_t ws_size,
                              hipStream_t stream) {
  const int*   x    = (const int*)d_in[0];
  const float* tab  = (const float*)d_in[1];
  const float* wih0 = (const float*)d_in[2];
  const float* whh0 = (const float*)d_in[3];
  const float* bih0 = (const float*)d_in[4];
  const float* bhh0 = (const float*)d_in[5];
  const float* wih1 = (const float*)d_in[6];
  const float* whh1 = (const float*)d_in[7];
  const float* bih1 = (const float*)d_in[8];
  const float* bhh1 = (const float*)d_in[9];
  const float* fcw  = (const float*)d_in[10];
  const float* fcb  = (const float*)d_in[11];

  char* p = (char*)d_ws;
  auto alloc = [&](size_t bytes) {
    void* r = (void*)p;
    p += (bytes + 255) & ~(size_t)255;
    return r;
  };
  half_t* wih0_h = (half_t*)alloc((size_t)G4_ * D_ * 2);
  half_t* wih1_h = (half_t*)alloc((size_t)G4_ * H_ * 2);
  half_t* wp0    = (half_t*)alloc((size_t)G4_ * H_ * 2);
  half_t* wp1    = (half_t*)alloc((size_t)G4_ * H_ * 2);
  float*  bias0  = (float*)alloc(G4_ * 4);
  float*  bias1  = (float*)alloc(G4_ * 4);
  float*  fcwt   = (float*)alloc((size_t)H_ * OUT_ * 4);
  half_t* hstate = (half_t*)alloc((size_t)2 * B_ * H_ * 2);
  float*  cstate = (float*)alloc((size_t)2 * B_ * H_ * 4);
  size_t fixed_used = (size_t)(p - (char*)d_ws);

  // Chunk length: largest power-of-2 CH <= 2048 with XG+HB fitting in ws.
  // per-CH bytes: XG = CH*B*1024*2 = CH*131072 ; HB = CH*B*256*2 = CH*32768
  int CH = 2048;
  while (CH > 32 &&
         fixed_used + (size_t)CH * (131072 + 32768) + (1u << 20) > ws_size)
    CH >>= 1;
  const int rowShift = __builtin_ctz(CH);
  half_t* XG = (half_t*)alloc((size_t)CH * B_ * G4_ * 2);
  half_t* HB = (half_t*)alloc((size_t)CH * B_ * H_ * 2);
  half_t* ebuf = (half_t*)d_out;   // 32 MB == out bytes; rows consumed before FC writes

  // prep (tiny)
  k_cvt_f16<<<512, 256, 0, stream>>>(wih0, wih0_h, G4_ * D_);
  k_cvt_f16<<<1024, 256, 0, stream>>>(wih1, wih1_h, G4_ * H_);
  k_pack_whh<<<1024, 256, 0, stream>>>(whh0, wp0);
  k_pack_whh<<<1024, 256, 0, stream>>>(whh1, wp1);
  k_bias<<<4, 256, 0, stream>>>(bih0, bhh0, bias0, G4_);
  k_bias<<<4, 256, 0, stream>>>(bih1, bhh1, bias1, G4_);
  k_fcwt<<<64, 256, 0, stream>>>(fcw, fcwt);

  k_embed<<<MTOT * (D_ / 8) / 256, 256, 0, stream>>>(x, tab, ebuf);

  const int M = B_ * CH;             // rows per chunk
  const int nchunks = T_ / CH;
  for (int ci = 0; ci < nchunks; ++ci) {
    const int t0 = ci * CH;
    // layer-0 projection: e (strided rows in d_out) -> XG
    k_gemm_f16<<<dim3(M / 128, G4_ / 128), 256, 0, stream>>>(
        ebuf, wih0_h, bias0, XG, D_, G4_, rowShift, T_, t0);
    // layer-0 recurrence: XG -> HB (h1)
    k_lstm<<<B_, 1024, 0, stream>>>(XG, (const uint4*)wp0, HB,
                                    cstate, hstate, CH, ci == 0);
    // layer-1 projection: HB (contiguous) -> XG (reuse)
    k_gemm_f16<<<dim3(M / 128, G4_ / 128), 256, 0, stream>>>(
        HB, wih1_h, bias1, XG, H_, G4_, rowShift, CH, 0);
    // layer-1 recurrence: XG -> HB (h2, reuse)
    k_lstm<<<B_, 1024, 0, stream>>>(XG, (const uint4*)wp1, HB,
                                    cstate + B_ * H_, hstate + B_ * H_, CH, ci == 0);
    // FC + softmax: HB -> out rows (b*T + t0 + t')
    k_fc_softmax<<<M / 4, 256, 0, stream>>>(HB, fcwt, fcb, (float*)d_out,
                                            rowShift, T_, t0);
  }
}